// Round 14
// baseline (285.839 us; speedup 1.0000x reference)
//
#include <hip/hip_runtime.h>
#include <hip/hip_fp16.h>

#define NN   100000
#define EE   1600000
#define BB   256
#define ES   94
#define EMB  64
#define HID  32
#define NB   391   // ceil(NN/256) buckets of 256 dst nodes
#define EPB  16    // edges per block in k_ef
#define DBINS 128  // degree bins for load-balance sort

__device__ __forceinline__ float lrelu(float x) { return x > 0.f ? x : 0.01f * x; }

// ================= fused scratch zeroing (replaces 4 memsets) =================
__global__ __launch_bounds__(256) void k_zero(int* __restrict__ bcnt,
                                              int* __restrict__ dcnt,
                                              int* __restrict__ flag,
                                              int* __restrict__ gcnt) {
    int i = blockIdx.x * 256 + threadIdx.x;
    if (i < NN) flag[i] = 0;
    if (i < NB) bcnt[i] = 0;
    if (i < DBINS) dcnt[i] = 0;
    if (i == 0) *gcnt = 0;
}

// ================= CSR build: LDS-binned counting sort =================

__global__ __launch_bounds__(256) void k_bhist(const int* __restrict__ dst,
                                               int* __restrict__ bcnt) {
    __shared__ int h[NB];
    int t = threadIdx.x;
    for (int i = t; i < NB; i += 256) h[i] = 0;
    __syncthreads();
    int e0 = blockIdx.x * 4096 + t * 16;
    if (e0 + 16 <= EE) {
        #pragma unroll
        for (int j = 0; j < 4; ++j) {
            int4 d = *(const int4*)&dst[e0 + j * 4];
            atomicAdd(&h[d.x >> 8], 1);
            atomicAdd(&h[d.y >> 8], 1);
            atomicAdd(&h[d.z >> 8], 1);
            atomicAdd(&h[d.w >> 8], 1);
        }
    } else {
        for (int e = e0; e < EE; ++e) atomicAdd(&h[dst[e] >> 8], 1);
    }
    __syncthreads();
    for (int i = t; i < NB; i += 256) if (h[i]) atomicAdd(&bcnt[i], h[i]);
}

__global__ void k_bscan(const int* __restrict__ bcnt, int* __restrict__ boff,
                        int* __restrict__ bcur, int* __restrict__ off) {
    __shared__ int sd[512];
    int t = threadIdx.x;
    int v = (t < NB) ? bcnt[t] : 0;
    sd[t] = v;
    __syncthreads();
    for (int o = 1; o < 512; o <<= 1) {
        int x = (t >= o) ? sd[t - o] : 0;
        __syncthreads();
        sd[t] += x;
        __syncthreads();
    }
    if (t < NB) { boff[t] = sd[t] - v; bcur[t] = sd[t] - v; }
    if (t == 0) { boff[NB] = EE; off[NN] = EE; }
}

__global__ __launch_bounds__(256) void k_bin(const int* __restrict__ src,
                                             const int* __restrict__ dst,
                                             int* __restrict__ bcur,
                                             int* __restrict__ bp) {
    __shared__ int h[NB];
    __shared__ int base[NB];
    int t = threadIdx.x;
    for (int i = t; i < NB; i += 256) h[i] = 0;
    __syncthreads();
    int e0 = blockIdx.x * 2048 + t * 8;
    int ve[8], vb[8], vr[8];
    if (e0 + 8 <= EE) {
        int4 s0 = *(const int4*)&src[e0];
        int4 s1 = *(const int4*)&src[e0 + 4];
        int4 d0 = *(const int4*)&dst[e0];
        int4 d1 = *(const int4*)&dst[e0 + 4];
        int ss[8] = {s0.x, s0.y, s0.z, s0.w, s1.x, s1.y, s1.z, s1.w};
        int dd[8] = {d0.x, d0.y, d0.z, d0.w, d1.x, d1.y, d1.z, d1.w};
        #pragma unroll
        for (int i = 0; i < 8; ++i) {
            int bk = dd[i] >> 8;
            vb[i] = bk;
            ve[i] = (ss[i] << 8) | (dd[i] & 255);
            vr[i] = atomicAdd(&h[bk], 1);
        }
    } else {
        #pragma unroll
        for (int i = 0; i < 8; ++i) {
            int e = e0 + i;
            if (e < EE) {
                int d = dst[e], s = src[e];
                int bk = d >> 8;
                vb[i] = bk;
                ve[i] = (s << 8) | (d & 255);
                vr[i] = atomicAdd(&h[bk], 1);
            } else vb[i] = -1;
        }
    }
    __syncthreads();
    for (int i = t; i < NB; i += 256) base[i] = h[i] ? atomicAdd(&bcur[i], h[i]) : 0;
    __syncthreads();
    #pragma unroll
    for (int i = 0; i < 8; ++i)
        if (vb[i] >= 0) bp[base[vb[i]] + vr[i]] = ve[i];
}

// per-bucket local CSR + node offsets + fused degree histogram
__global__ __launch_bounds__(256) void k_bcsr(const int* __restrict__ boff,
                                              const int* __restrict__ bp,
                                              int* __restrict__ off,
                                              int* __restrict__ csr,
                                              int* __restrict__ dcnt) {
    __shared__ int hist[256];
    __shared__ int loc[256];
    __shared__ int dh[DBINS];
    int t = threadIdx.x;
    int b = blockIdx.x;
    int e0 = boff[b], e1 = boff[b + 1];
    hist[t] = 0;
    if (t < DBINS) dh[t] = 0;
    __syncthreads();
    for (int e = e0 + t; e < e1; e += 256) atomicAdd(&hist[bp[e] & 255], 1);
    __syncthreads();
    int v = hist[t];
    loc[t] = v;
    __syncthreads();
    for (int o = 1; o < 256; o <<= 1) {
        int x = (t >= o) ? loc[t - o] : 0;
        __syncthreads();
        loc[t] += x;
        __syncthreads();
    }
    int excl = loc[t] - v;
    int n = (b << 8) + t;
    bool valid = n < NN;
    if (valid) off[n] = e0 + excl;
    hist[t] = excl;   // reuse as cursor
    int d = v > DBINS - 1 ? DBINS - 1 : v;
    if (valid) atomicAdd(&dh[d], 1);
    __syncthreads();
    for (int e = e0 + t; e < e1; e += 256) {
        int pv = bp[e];
        int p = e0 + atomicAdd(&hist[pv & 255], 1);
        csr[p] = pv >> 8;
    }
    if (t < DBINS && dh[t]) atomicAdd(&dcnt[t], dh[t]);
}

// ================= degree-DESCENDING permutation (LPT scheduling) =================
__global__ void k_dscan(const int* __restrict__ dcnt, int* __restrict__ dcur) {
    __shared__ int sd[DBINS];
    int t = threadIdx.x;
    int v = dcnt[t];
    sd[t] = v;
    __syncthreads();
    for (int o = 1; o < DBINS; o <<= 1) {
        int x = (t >= o) ? sd[t - o] : 0;
        __syncthreads();
        sd[t] += x;
        __syncthreads();
    }
    dcur[t] = NN - sd[t];
}

__global__ __launch_bounds__(256) void k_dperm(const int* __restrict__ off,
                                               int* __restrict__ dcur,
                                               int* __restrict__ perm) {
    __shared__ int h[DBINS];
    __shared__ int base[DBINS];
    int t = threadIdx.x;
    if (t < DBINS) h[t] = 0;
    __syncthreads();
    int n = blockIdx.x * 256 + t;
    int d = 0, r = 0;
    if (n < NN) {
        d = off[n + 1] - off[n];
        if (d > DBINS - 1) d = DBINS - 1;
        r = atomicAdd(&h[d], 1);
    }
    __syncthreads();
    if (t < DBINS) base[t] = h[t] ? atomicAdd(&dcur[t], h[t]) : 0;
    __syncthreads();
    if (n < NN) perm[base[d] + r] = n;
}

// ================= mark + compact nodes needed by the mask =================
__global__ __launch_bounds__(256) void k_mark(const int* __restrict__ mask,
                                              const int* __restrict__ esrc,
                                              const int* __restrict__ edst,
                                              int* __restrict__ flag) {
    int i = blockIdx.x * 256 + threadIdx.x;
    if (i < BB * ES) {
        int e = mask[i];
        flag[esrc[e]] = 1;
        flag[edst[e]] = 1;
    }
}

__global__ __launch_bounds__(256) void k_compact(const int* __restrict__ perm,
                                                 const int* __restrict__ flag,
                                                 int* __restrict__ list,
                                                 int* __restrict__ gcnt) {
    __shared__ int loc[256];
    __shared__ int sbase;
    int t = threadIdx.x;
    int i = blockIdx.x * 256 + t;
    int n = (i < NN) ? perm[i] : 0;
    int f = (i < NN) ? flag[n] : 0;
    loc[t] = f;
    __syncthreads();
    for (int o = 1; o < 256; o <<= 1) {
        int x = (t >= o) ? loc[t - o] : 0;
        __syncthreads();
        loc[t] += x;
        __syncthreads();
    }
    if (t == 255 && loc[255]) sbase = atomicAdd(gcnt, loc[255]);
    __syncthreads();
    if (f) list[sbase + loc[t] - 1] = n;
}

// ================= layer 1: algebraic (coord gather only; Wg via L1) =================
__global__ __launch_bounds__(256) void k_gg0(const float2* __restrict__ coordv,
                                             const int* __restrict__ off,
                                             const int* __restrict__ csr,
                                             const float* __restrict__ Wn,
                                             const float* __restrict__ bn,
                                             const float* __restrict__ Wg,
                                             const float* __restrict__ bg,
                                             float* __restrict__ hout,
                                             __half* __restrict__ houtH) {
    __shared__ float aggL[16][EMB + 4];
    int t = threadIdx.x;
    int g = t >> 4;
    int r = t & 15;
    int r4 = r * 4;
    int n = blockIdx.x * 16 + g;
    int s0 = off[n], s1 = off[n + 1];
    float sx = 0.f, sy = 0.f;
    for (int e = s0 + r; e < s1; e += 16) {
        float2 c = coordv[csr[e]];
        sx += c.x; sy += c.y;
    }
    #pragma unroll
    for (int o = 8; o >= 1; o >>= 1) {
        sx += __shfl_xor(sx, o);
        sy += __shfl_xor(sy, o);
    }
    float deg = (float)(s1 - s0);
    float4 wn0 = *(const float4*)&Wn[r4];
    float4 wn1 = *(const float4*)&Wn[EMB + r4];
    float4 bnv = *(const float4*)&bn[r4];
    aggL[g][r4 + 0] = sx * wn0.x + sy * wn1.x + deg * bnv.x;
    aggL[g][r4 + 1] = sx * wn0.y + sy * wn1.y + deg * bnv.y;
    aggL[g][r4 + 2] = sx * wn0.z + sy * wn1.z + deg * bnv.z;
    aggL[g][r4 + 3] = sx * wn0.w + sy * wn1.w + deg * bnv.w;
    __syncthreads();
    const float4* Wg4 = (const float4*)Wg;
    float4 acc = *(const float4*)&bg[r4];
    #pragma unroll
    for (int k = 0; k < EMB; ++k) {
        float a = aggL[g][k];
        float4 w = Wg4[k * 16 + r];
        acc.x += a * w.x; acc.y += a * w.y; acc.z += a * w.z; acc.w += a * w.w;
    }
    float2 c = coordv[n];
    float4 hb;
    hb.x = c.x * wn0.x + c.y * wn1.x + bnv.x + lrelu(acc.x);
    hb.y = c.x * wn0.y + c.y * wn1.y + bnv.y + lrelu(acc.y);
    hb.z = c.x * wn0.z + c.y * wn1.z + bnv.z + lrelu(acc.z);
    hb.w = c.x * wn0.w + c.y * wn1.w + bnv.w + lrelu(acc.w);
    *(float4*)&hout[n * EMB + r4] = hb;
    __half2 o0 = __floats2half2_rn(hb.x, hb.y);
    __half2 o1 = __floats2half2_rn(hb.z, hb.w);
    uint2 pk;
    pk.x = *(unsigned int*)&o0;
    pk.y = *(unsigned int*)&o1;
    *(uint2*)&houtH[n * EMB + r4] = pk;
}

// ================= layer 2: fp16 gather (uint2, 16 lanes/row, 8-deep) =================
__global__ __launch_bounds__(256) void k_gg(const float* __restrict__ hin,
                                            const __half* __restrict__ hinH,
                                            const int* __restrict__ off,
                                            const int* __restrict__ csr,
                                            const int* __restrict__ perm,
                                            const float* __restrict__ Wg,
                                            const float* __restrict__ bg,
                                            float* __restrict__ hout,
                                            __half* __restrict__ houtH) {
    __shared__ float aggL[16][EMB + 4];
    int t = threadIdx.x;
    int g = t >> 4;
    int r = t & 15;
    int r4 = r * 4;
    int n = perm[blockIdx.x * 16 + g];
    int s0 = off[n], s1 = off[n + 1];
    float ax = 0.f, ay = 0.f, az = 0.f, aw = 0.f;
    int e = s0;
    for (; e + 8 <= s1; e += 8) {
        int idx[8];
        #pragma unroll
        for (int j = 0; j < 8; ++j) idx[j] = csr[e + j];
        uint2 raw[8];
        #pragma unroll
        for (int j = 0; j < 8; ++j) raw[j] = *(const uint2*)&hinH[idx[j] * EMB + r4];
        #pragma unroll
        for (int j = 0; j < 8; ++j) {
            float2 f0 = __half22float2(*(__half2*)&raw[j].x);
            float2 f1 = __half22float2(*(__half2*)&raw[j].y);
            ax += f0.x; ay += f0.y; az += f1.x; aw += f1.y;
        }
    }
    for (; e < s1; ++e) {
        uint2 raw = *(const uint2*)&hinH[csr[e] * EMB + r4];
        float2 f0 = __half22float2(*(__half2*)&raw.x);
        float2 f1 = __half22float2(*(__half2*)&raw.y);
        ax += f0.x; ay += f0.y; az += f1.x; aw += f1.y;
    }
    aggL[g][r4 + 0] = ax;
    aggL[g][r4 + 1] = ay;
    aggL[g][r4 + 2] = az;
    aggL[g][r4 + 3] = aw;
    __syncthreads();
    const float4* Wg4 = (const float4*)Wg;
    float4 acc = *(const float4*)&bg[r4];
    #pragma unroll
    for (int k = 0; k < EMB; ++k) {
        float a = aggL[g][k];
        float4 w = Wg4[k * 16 + r];
        acc.x += a * w.x; acc.y += a * w.y; acc.z += a * w.z; acc.w += a * w.w;
    }
    float4 hb = *(const float4*)&hin[n * EMB + r4];
    hb.x += lrelu(acc.x);
    hb.y += lrelu(acc.y);
    hb.z += lrelu(acc.z);
    hb.w += lrelu(acc.w);
    *(float4*)&hout[n * EMB + r4] = hb;
    __half2 o0 = __floats2half2_rn(hb.x, hb.y);
    __half2 o1 = __floats2half2_rn(hb.z, hb.w);
    uint2 pk;
    pk.x = *(unsigned int*)&o0;
    pk.y = *(unsigned int*)&o1;
    *(uint2*)&houtH[n * EMB + r4] = pk;
}

// ================= layer 3: pruned fp16 gather (uint2, 8-deep) =================
__global__ __launch_bounds__(256) void k_gg3(const float* __restrict__ hin,
                                             const __half* __restrict__ hinH,
                                             const int* __restrict__ off,
                                             const int* __restrict__ csr,
                                             const int* __restrict__ list,
                                             const int* __restrict__ gcnt,
                                             const float* __restrict__ Wg,
                                             const float* __restrict__ bg,
                                             float* __restrict__ hout) {
    __shared__ float aggL[16][EMB + 4];
    int cnt = *gcnt;
    if (blockIdx.x * 16 >= cnt) return;
    int t = threadIdx.x;
    int g = t >> 4;
    int r = t & 15;
    int r4 = r * 4;
    int li = blockIdx.x * 16 + g;
    bool act = li < cnt;
    int n = act ? list[li] : 0;
    int s0 = 0, s1 = 0;
    if (act) { s0 = off[n]; s1 = off[n + 1]; }
    float ax = 0.f, ay = 0.f, az = 0.f, aw = 0.f;
    int e = s0;
    for (; e + 8 <= s1; e += 8) {
        int idx[8];
        #pragma unroll
        for (int j = 0; j < 8; ++j) idx[j] = csr[e + j];
        uint2 raw[8];
        #pragma unroll
        for (int j = 0; j < 8; ++j) raw[j] = *(const uint2*)&hinH[idx[j] * EMB + r4];
        #pragma unroll
        for (int j = 0; j < 8; ++j) {
            float2 f0 = __half22float2(*(__half2*)&raw[j].x);
            float2 f1 = __half22float2(*(__half2*)&raw[j].y);
            ax += f0.x; ay += f0.y; az += f1.x; aw += f1.y;
        }
    }
    for (; e < s1; ++e) {
        uint2 raw = *(const uint2*)&hinH[csr[e] * EMB + r4];
        float2 f0 = __half22float2(*(__half2*)&raw.x);
        float2 f1 = __half22float2(*(__half2*)&raw.y);
        ax += f0.x; ay += f0.y; az += f1.x; aw += f1.y;
    }
    aggL[g][r4 + 0] = ax;
    aggL[g][r4 + 1] = ay;
    aggL[g][r4 + 2] = az;
    aggL[g][r4 + 3] = aw;
    __syncthreads();
    const float4* Wg4 = (const float4*)Wg;
    float4 acc = *(const float4*)&bg[r4];
    #pragma unroll
    for (int k = 0; k < EMB; ++k) {
        float a = aggL[g][k];
        float4 w = Wg4[k * 16 + r];
        acc.x += a * w.x; acc.y += a * w.y; acc.z += a * w.z; acc.w += a * w.w;
    }
    if (act) {
        float4 hb = *(const float4*)&hin[n * EMB + r4];
        hb.x += lrelu(acc.x);
        hb.y += lrelu(acc.y);
        hb.z += lrelu(acc.z);
        hb.w += lrelu(acc.w);
        *(float4*)&hout[n * EMB + r4] = hb;
    }
}

// ================= edge features + MLP.linear (data-parallel) =================
__global__ __launch_bounds__(256) void k_ef(
    const float* __restrict__ h, const int* __restrict__ esrc, const int* __restrict__ edst,
    const int* __restrict__ mask,
    const float* __restrict__ WeS, const float* __restrict__ WeD, const float* __restrict__ be,
    const float* __restrict__ W1, const float* __restrict__ b1,
    const float* __restrict__ W2, const float* __restrict__ b2,
    float* __restrict__ xout)
{
    __shared__ float WeSL[EMB * EMB];
    __shared__ float WeDL[EMB * EMB];
    __shared__ float W1L[EMB * HID];
    __shared__ float hsL[EPB][EMB + 4];
    __shared__ float hdL[EPB][EMB + 4];
    int t = threadIdx.x;
    for (int i = t; i < EMB * EMB / 4; i += 256) {
        ((float4*)WeSL)[i] = ((const float4*)WeS)[i];
        ((float4*)WeDL)[i] = ((const float4*)WeD)[i];
    }
    for (int i = t; i < EMB * HID / 4; i += 256) ((float4*)W1L)[i] = ((const float4*)W1)[i];
    int g = t >> 4, r = t & 15, r4 = r * 4;
    int idx = blockIdx.x * EPB + g;
    int e = mask[idx];
    int s = esrc[e], d = edst[e];
    float4 hs4 = *(const float4*)&h[s * EMB + r4];
    float4 hd4 = *(const float4*)&h[d * EMB + r4];
    *(float4*)&hsL[g][r4] = hs4;
    *(float4*)&hdL[g][r4] = hd4;
    __syncthreads();
    float4 acc = *(const float4*)&be[r4];
    #pragma unroll
    for (int k = 0; k < EMB; ++k) {
        float a = hsL[g][k];
        float c = hdL[g][k];
        float4 w1 = *(const float4*)&WeSL[k * EMB + r4];
        float4 w2 = *(const float4*)&WeDL[k * EMB + r4];
        acc.x += a * w1.x + c * w2.x;
        acc.y += a * w1.y + c * w2.y;
        acc.z += a * w1.z + c * w2.z;
        acc.w += a * w1.w + c * w2.w;
    }
    __syncthreads();
    *(float4*)&hsL[g][r4] = acc;
    __syncthreads();
    float a1 = b1[r], a2 = b1[r + 16];
    #pragma unroll
    for (int k = 0; k < EMB; ++k) {
        float ek = hsL[g][k];
        a1 += ek * W1L[k * HID + r];
        a2 += ek * W1L[k * HID + r + 16];
    }
    float y1 = lrelu(a1), y2 = lrelu(a2);
    float p = y1 * W2[r] + y2 * W2[r + 16];
    p += __shfl_xor(p, 1);
    p += __shfl_xor(p, 2);
    p += __shfl_xor(p, 4);
    p += __shfl_xor(p, 8);
    if (r == 0) xout[idx] = p + b2[0];
}

// ================= decoder =================
__global__ __launch_bounds__(64) void k_dec(const float* __restrict__ xout,
                                            const float* __restrict__ Wd1,
                                            const float* __restrict__ bd1,
                                            const float* __restrict__ Wd2,
                                            const float* __restrict__ bd2,
                                            float* __restrict__ out) {
    int b = blockIdx.x, t = threadIdx.x;
    float z = 0.f;
    if (t < HID) {
        float acc = bd1[t];
        for (int i = 0; i < ES; ++i) acc += xout[b * ES + i] * Wd1[i * HID + t];
        z = lrelu(acc) * Wd2[t];
    }
    z += __shfl_xor(z, 1);
    z += __shfl_xor(z, 2);
    z += __shfl_xor(z, 4);
    z += __shfl_xor(z, 8);
    z += __shfl_xor(z, 16);
    if (t == 0) out[b] = z + bd2[0];
}

extern "C" void kernel_launch(void* const* d_in, const int* in_sizes, int n_in,
                              void* d_out, int out_size, void* d_ws, size_t ws_size,
                              hipStream_t stream) {
    const float* coord = (const float*)d_in[0];
    const int*   esrc  = (const int*)d_in[1];
    const int*   edst  = (const int*)d_in[2];
    const int*   mask  = (const int*)d_in[3];
    const float* Wn    = (const float*)d_in[4];
    const float* bn    = (const float*)d_in[5];
    const float* Wgnn  = (const float*)d_in[6];
    const float* bgnn  = (const float*)d_in[7];
    const float* WeS   = (const float*)d_in[8];
    const float* WeD   = (const float*)d_in[9];
    const float* be    = (const float*)d_in[10];
    const float* W1    = (const float*)d_in[11];
    const float* b1    = (const float*)d_in[12];
    const float* W2    = (const float*)d_in[13];
    const float* b2    = (const float*)d_in[14];
    const float* Wd1   = (const float*)d_in[15];
    const float* bd1   = (const float*)d_in[16];
    const float* Wd2   = (const float*)d_in[17];
    const float* bd2   = (const float*)d_in[18];
    float* out = (float*)d_out;

    char* ws = (char*)d_ws;
    size_t o = 0;
    auto alloc = [&](size_t bytes) {
        void* p = ws + o;
        o = (o + bytes + 255) & ~(size_t)255;
        return p;
    };
    float* hA    = (float*)alloc((size_t)NN * EMB * 4);
    float* hB    = (float*)alloc((size_t)NN * EMB * 4);
    __half* hAh  = (__half*)alloc((size_t)NN * EMB * 2);
    __half* hBh  = (__half*)alloc((size_t)NN * EMB * 2);
    int* off    = (int*)alloc((size_t)(NN + 1) * 4);
    int* csr    = (int*)alloc((size_t)EE * 4);
    int* bp     = (int*)alloc((size_t)EE * 4);
    int* bcnt   = (int*)alloc((size_t)NB * 4);
    int* boff   = (int*)alloc((size_t)(NB + 1) * 4);
    int* bcur   = (int*)alloc((size_t)NB * 4);
    int* perm   = (int*)alloc((size_t)NN * 4);
    int* dcnt   = (int*)alloc((size_t)DBINS * 4);
    int* dcur   = (int*)alloc((size_t)DBINS * 4);
    int* flag   = (int*)alloc((size_t)NN * 4);
    int* list   = (int*)alloc((size_t)NN * 4);
    int* gcnt   = (int*)alloc(256);
    float* xout = (float*)alloc((size_t)BB * ES * 4);
    (void)ws_size; (void)in_sizes; (void)n_in; (void)out_size;

    const float2* coordv = (const float2*)coord;

    // fused scratch zeroing (every launch: harness doesn't re-poison)
    k_zero<<<(NN + 255) / 256, 256, 0, stream>>>(bcnt, dcnt, flag, gcnt);

    // mark masked-edge endpoints (independent of CSR chain)
    k_mark<<<(BB * ES + 255) / 256, 256, 0, stream>>>(mask, esrc, edst, flag);

    // CSR build (+ fused degree histogram)
    k_bhist<<<(EE + 4095) / 4096, 256, 0, stream>>>(edst, bcnt);
    k_bscan<<<1, 512, 0, stream>>>(bcnt, boff, bcur, off);
    k_bin<<<(EE + 2047) / 2048, 256, 0, stream>>>(esrc, edst, bcur, bp);
    k_bcsr<<<NB, 256, 0, stream>>>(boff, bp, off, csr, dcnt);

    // degree-descending permutation (LPT)
    k_dscan<<<1, DBINS, 0, stream>>>(dcnt, dcur);
    k_dperm<<<(NN + 255) / 256, 256, 0, stream>>>(off, dcur, perm);

    // compact needed-node list in perm (degree) order
    k_compact<<<(NN + 255) / 256, 256, 0, stream>>>(perm, flag, list, gcnt);

    // layer 1 (algebraic): h1 fp32 -> hA, fp16 shadow -> hAh
    k_gg0<<<NN / 16, 256, 0, stream>>>(coordv, off, csr, Wn, bn,
                                       Wgnn, bgnn, hA, hAh);

    // layer 2: fp16 gather, fp32 residual; h2 -> hB + hBh
    k_gg<<<NN / 16, 256, 0, stream>>>(hA, hAh, off, csr, perm,
                                      Wgnn + (size_t)1 * EMB * EMB,
                                      bgnn + (size_t)1 * EMB, hB, hBh);

    // layer 3: pruned fp16 gather; h3 rows -> hA
    k_gg3<<<(NN + 15) / 16, 256, 0, stream>>>(hB, hBh, off, csr, list, gcnt,
                                              Wgnn + (size_t)2 * EMB * EMB,
                                              bgnn + (size_t)2 * EMB, hA);

    // masked edgewise features + MLP + decoder
    k_ef<<<BB * ES / EPB, 256, 0, stream>>>(hA, esrc, edst, mask, WeS, WeD, be,
                                            W1, b1, W2, b2, xout);
    k_dec<<<BB, 64, 0, stream>>>(xout, Wd1, bd1, Wd2, bd2, out);
}

// Round 15
// 217.383 us; speedup vs baseline: 1.3149x; 1.3149x over previous
//
#include <hip/hip_runtime.h>
#include <hip/hip_fp16.h>

#define NN   100000
#define EE   1600000
#define BB   256
#define ES   94
#define EMB  64
#define HID  32
#define NB   391   // ceil(NN/256) buckets of 256 dst nodes
#define EPB  16    // edges per block in k_ef
#define DBINS 128  // degree bins for load-balance sort

__device__ __forceinline__ float lrelu(float x) { return x > 0.f ? x : 0.01f * x; }

// ================= fused scratch zeroing (replaces 4 memsets) =================
__global__ __launch_bounds__(256) void k_zero(int* __restrict__ bcnt,
                                              int* __restrict__ dcnt,
                                              int* __restrict__ flag,
                                              int* __restrict__ gcnt) {
    int i = blockIdx.x * 256 + threadIdx.x;
    if (i < NN) flag[i] = 0;
    if (i < NB) bcnt[i] = 0;
    if (i < DBINS) dcnt[i] = 0;
    if (i == 0) *gcnt = 0;
}

// ================= CSR build: LDS-binned counting sort =================

__global__ __launch_bounds__(256) void k_bhist(const int* __restrict__ dst,
                                               int* __restrict__ bcnt) {
    __shared__ int h[NB];
    int t = threadIdx.x;
    for (int i = t; i < NB; i += 256) h[i] = 0;
    __syncthreads();
    int e0 = blockIdx.x * 4096 + t * 16;
    if (e0 + 16 <= EE) {
        #pragma unroll
        for (int j = 0; j < 4; ++j) {
            int4 d = *(const int4*)&dst[e0 + j * 4];
            atomicAdd(&h[d.x >> 8], 1);
            atomicAdd(&h[d.y >> 8], 1);
            atomicAdd(&h[d.z >> 8], 1);
            atomicAdd(&h[d.w >> 8], 1);
        }
    } else {
        for (int e = e0; e < EE; ++e) atomicAdd(&h[dst[e] >> 8], 1);
    }
    __syncthreads();
    for (int i = t; i < NB; i += 256) if (h[i]) atomicAdd(&bcnt[i], h[i]);
}

__global__ void k_bscan(const int* __restrict__ bcnt, int* __restrict__ boff,
                        int* __restrict__ bcur, int* __restrict__ off) {
    __shared__ int sd[512];
    int t = threadIdx.x;
    int v = (t < NB) ? bcnt[t] : 0;
    sd[t] = v;
    __syncthreads();
    for (int o = 1; o < 512; o <<= 1) {
        int x = (t >= o) ? sd[t - o] : 0;
        __syncthreads();
        sd[t] += x;
        __syncthreads();
    }
    if (t < NB) { boff[t] = sd[t] - v; bcur[t] = sd[t] - v; }
    if (t == 0) { boff[NB] = EE; off[NN] = EE; }
}

__global__ __launch_bounds__(256) void k_bin(const int* __restrict__ src,
                                             const int* __restrict__ dst,
                                             int* __restrict__ bcur,
                                             int* __restrict__ bp) {
    __shared__ int h[NB];
    __shared__ int base[NB];
    int t = threadIdx.x;
    for (int i = t; i < NB; i += 256) h[i] = 0;
    __syncthreads();
    int e0 = blockIdx.x * 2048 + t * 8;
    int ve[8], vb[8], vr[8];
    if (e0 + 8 <= EE) {
        int4 s0 = *(const int4*)&src[e0];
        int4 s1 = *(const int4*)&src[e0 + 4];
        int4 d0 = *(const int4*)&dst[e0];
        int4 d1 = *(const int4*)&dst[e0 + 4];
        int ss[8] = {s0.x, s0.y, s0.z, s0.w, s1.x, s1.y, s1.z, s1.w};
        int dd[8] = {d0.x, d0.y, d0.z, d0.w, d1.x, d1.y, d1.z, d1.w};
        #pragma unroll
        for (int i = 0; i < 8; ++i) {
            int bk = dd[i] >> 8;
            vb[i] = bk;
            ve[i] = (ss[i] << 8) | (dd[i] & 255);
            vr[i] = atomicAdd(&h[bk], 1);
        }
    } else {
        #pragma unroll
        for (int i = 0; i < 8; ++i) {
            int e = e0 + i;
            if (e < EE) {
                int d = dst[e], s = src[e];
                int bk = d >> 8;
                vb[i] = bk;
                ve[i] = (s << 8) | (d & 255);
                vr[i] = atomicAdd(&h[bk], 1);
            } else vb[i] = -1;
        }
    }
    __syncthreads();
    for (int i = t; i < NB; i += 256) base[i] = h[i] ? atomicAdd(&bcur[i], h[i]) : 0;
    __syncthreads();
    #pragma unroll
    for (int i = 0; i < 8; ++i)
        if (vb[i] >= 0) bp[base[vb[i]] + vr[i]] = ve[i];
}

// per-bucket local CSR + node offsets + fused degree histogram
__global__ __launch_bounds__(256) void k_bcsr(const int* __restrict__ boff,
                                              const int* __restrict__ bp,
                                              int* __restrict__ off,
                                              int* __restrict__ csr,
                                              int* __restrict__ dcnt) {
    __shared__ int hist[256];
    __shared__ int loc[256];
    __shared__ int dh[DBINS];
    int t = threadIdx.x;
    int b = blockIdx.x;
    int e0 = boff[b], e1 = boff[b + 1];
    hist[t] = 0;
    if (t < DBINS) dh[t] = 0;
    __syncthreads();
    for (int e = e0 + t; e < e1; e += 256) atomicAdd(&hist[bp[e] & 255], 1);
    __syncthreads();
    int v = hist[t];
    loc[t] = v;
    __syncthreads();
    for (int o = 1; o < 256; o <<= 1) {
        int x = (t >= o) ? loc[t - o] : 0;
        __syncthreads();
        loc[t] += x;
        __syncthreads();
    }
    int excl = loc[t] - v;
    int n = (b << 8) + t;
    bool valid = n < NN;
    if (valid) off[n] = e0 + excl;
    hist[t] = excl;   // reuse as cursor
    int d = v > DBINS - 1 ? DBINS - 1 : v;
    if (valid) atomicAdd(&dh[d], 1);
    __syncthreads();
    for (int e = e0 + t; e < e1; e += 256) {
        int pv = bp[e];
        int p = e0 + atomicAdd(&hist[pv & 255], 1);
        csr[p] = pv >> 8;
    }
    if (t < DBINS && dh[t]) atomicAdd(&dcnt[t], dh[t]);
}

// ================= degree-DESCENDING permutation (LPT scheduling) =================
__global__ void k_dscan(const int* __restrict__ dcnt, int* __restrict__ dcur) {
    __shared__ int sd[DBINS];
    int t = threadIdx.x;
    int v = dcnt[t];
    sd[t] = v;
    __syncthreads();
    for (int o = 1; o < DBINS; o <<= 1) {
        int x = (t >= o) ? sd[t - o] : 0;
        __syncthreads();
        sd[t] += x;
        __syncthreads();
    }
    dcur[t] = NN - sd[t];
}

__global__ __launch_bounds__(256) void k_dperm(const int* __restrict__ off,
                                               int* __restrict__ dcur,
                                               int* __restrict__ perm) {
    __shared__ int h[DBINS];
    __shared__ int base[DBINS];
    int t = threadIdx.x;
    if (t < DBINS) h[t] = 0;
    __syncthreads();
    int n = blockIdx.x * 256 + t;
    int d = 0, r = 0;
    if (n < NN) {
        d = off[n + 1] - off[n];
        if (d > DBINS - 1) d = DBINS - 1;
        r = atomicAdd(&h[d], 1);
    }
    __syncthreads();
    if (t < DBINS) base[t] = h[t] ? atomicAdd(&dcur[t], h[t]) : 0;
    __syncthreads();
    if (n < NN) perm[base[d] + r] = n;
}

// ================= mark + compact nodes needed by the mask =================
__global__ __launch_bounds__(256) void k_mark(const int* __restrict__ mask,
                                              const int* __restrict__ esrc,
                                              const int* __restrict__ edst,
                                              int* __restrict__ flag) {
    int i = blockIdx.x * 256 + threadIdx.x;
    if (i < BB * ES) {
        int e = mask[i];
        flag[esrc[e]] = 1;
        flag[edst[e]] = 1;
    }
}

__global__ __launch_bounds__(256) void k_compact(const int* __restrict__ perm,
                                                 const int* __restrict__ flag,
                                                 int* __restrict__ list,
                                                 int* __restrict__ gcnt) {
    __shared__ int loc[256];
    __shared__ int sbase;
    int t = threadIdx.x;
    int i = blockIdx.x * 256 + t;
    int n = (i < NN) ? perm[i] : 0;
    int f = (i < NN) ? flag[n] : 0;
    loc[t] = f;
    __syncthreads();
    for (int o = 1; o < 256; o <<= 1) {
        int x = (t >= o) ? loc[t - o] : 0;
        __syncthreads();
        loc[t] += x;
        __syncthreads();
    }
    if (t == 255 && loc[255]) sbase = atomicAdd(gcnt, loc[255]);
    __syncthreads();
    if (f) list[sbase + loc[t] - 1] = n;
}

// ================= layer 1: algebraic (coord gather only) =================
__global__ __launch_bounds__(256) void k_gg0(const float2* __restrict__ coordv,
                                             const int* __restrict__ off,
                                             const int* __restrict__ csr,
                                             const float* __restrict__ Wn,
                                             const float* __restrict__ bn,
                                             const float* __restrict__ Wg,
                                             const float* __restrict__ bg,
                                             float* __restrict__ hout,
                                             __half* __restrict__ houtH) {
    __shared__ float WgL[EMB * EMB];
    __shared__ float aggL[16][EMB + 4];
    int t = threadIdx.x;
    for (int i = t * 4; i < EMB * EMB; i += 256 * 4)
        *(float4*)&WgL[i] = *(const float4*)&Wg[i];
    int g = t >> 4;
    int r = t & 15;
    int r4 = r * 4;
    int n = blockIdx.x * 16 + g;
    int s0 = off[n], s1 = off[n + 1];
    float sx = 0.f, sy = 0.f;
    for (int e = s0 + r; e < s1; e += 16) {
        float2 c = coordv[csr[e]];
        sx += c.x; sy += c.y;
    }
    #pragma unroll
    for (int o = 8; o >= 1; o >>= 1) {
        sx += __shfl_xor(sx, o);
        sy += __shfl_xor(sy, o);
    }
    float deg = (float)(s1 - s0);
    float4 wn0 = *(const float4*)&Wn[r4];
    float4 wn1 = *(const float4*)&Wn[EMB + r4];
    float4 bnv = *(const float4*)&bn[r4];
    aggL[g][r4 + 0] = sx * wn0.x + sy * wn1.x + deg * bnv.x;
    aggL[g][r4 + 1] = sx * wn0.y + sy * wn1.y + deg * bnv.y;
    aggL[g][r4 + 2] = sx * wn0.z + sy * wn1.z + deg * bnv.z;
    aggL[g][r4 + 3] = sx * wn0.w + sy * wn1.w + deg * bnv.w;
    __syncthreads();
    float4 acc = *(const float4*)&bg[r4];
    #pragma unroll
    for (int k = 0; k < EMB; ++k) {
        float a = aggL[g][k];
        float4 w = *(const float4*)&WgL[k * EMB + r4];
        acc.x += a * w.x; acc.y += a * w.y; acc.z += a * w.z; acc.w += a * w.w;
    }
    float2 c = coordv[n];
    float4 hb;
    hb.x = c.x * wn0.x + c.y * wn1.x + bnv.x + lrelu(acc.x);
    hb.y = c.x * wn0.y + c.y * wn1.y + bnv.y + lrelu(acc.y);
    hb.z = c.x * wn0.z + c.y * wn1.z + bnv.z + lrelu(acc.z);
    hb.w = c.x * wn0.w + c.y * wn1.w + bnv.w + lrelu(acc.w);
    *(float4*)&hout[n * EMB + r4] = hb;
    __half2 o0 = __floats2half2_rn(hb.x, hb.y);
    __half2 o1 = __floats2half2_rn(hb.z, hb.w);
    uint2 pk;
    pk.x = *(unsigned int*)&o0;
    pk.y = *(unsigned int*)&o1;
    *(uint2*)&houtH[n * EMB + r4] = pk;
}

// ================= layer 2: fp16 gather (uint2, 16 lanes/row, 8-deep) =================
__global__ __launch_bounds__(256) void k_gg(const float* __restrict__ hin,
                                            const __half* __restrict__ hinH,
                                            const int* __restrict__ off,
                                            const int* __restrict__ csr,
                                            const int* __restrict__ perm,
                                            const float* __restrict__ Wg,
                                            const float* __restrict__ bg,
                                            float* __restrict__ hout,
                                            __half* __restrict__ houtH) {
    __shared__ float WgL[EMB * EMB];      // 16 KB
    __shared__ float aggL[16][EMB + 4];
    int t = threadIdx.x;
    for (int i = t * 4; i < EMB * EMB; i += 256 * 4)
        *(float4*)&WgL[i] = *(const float4*)&Wg[i];
    int g = t >> 4;
    int r4 = (t & 15) * 4;
    int n = perm[blockIdx.x * 16 + g];
    int s0 = off[n], s1 = off[n + 1];
    float ax = 0.f, ay = 0.f, az = 0.f, aw = 0.f;
    int e = s0;
    for (; e + 8 <= s1; e += 8) {
        int idx[8];
        #pragma unroll
        for (int j = 0; j < 8; ++j) idx[j] = csr[e + j];
        uint2 raw[8];
        #pragma unroll
        for (int j = 0; j < 8; ++j) raw[j] = *(const uint2*)&hinH[idx[j] * EMB + r4];
        #pragma unroll
        for (int j = 0; j < 8; ++j) {
            float2 f0 = __half22float2(*(__half2*)&raw[j].x);
            float2 f1 = __half22float2(*(__half2*)&raw[j].y);
            ax += f0.x; ay += f0.y; az += f1.x; aw += f1.y;
        }
    }
    for (; e < s1; ++e) {
        uint2 raw = *(const uint2*)&hinH[csr[e] * EMB + r4];
        float2 f0 = __half22float2(*(__half2*)&raw.x);
        float2 f1 = __half22float2(*(__half2*)&raw.y);
        ax += f0.x; ay += f0.y; az += f1.x; aw += f1.y;
    }
    aggL[g][r4 + 0] = ax;
    aggL[g][r4 + 1] = ay;
    aggL[g][r4 + 2] = az;
    aggL[g][r4 + 3] = aw;
    __syncthreads();
    float4 acc = *(const float4*)&bg[r4];
    #pragma unroll
    for (int k = 0; k < EMB; ++k) {
        float a = aggL[g][k];
        float4 w = *(const float4*)&WgL[k * EMB + r4];
        acc.x += a * w.x; acc.y += a * w.y; acc.z += a * w.z; acc.w += a * w.w;
    }
    float4 hb = *(const float4*)&hin[n * EMB + r4];
    hb.x += lrelu(acc.x);
    hb.y += lrelu(acc.y);
    hb.z += lrelu(acc.z);
    hb.w += lrelu(acc.w);
    *(float4*)&hout[n * EMB + r4] = hb;
    __half2 o0 = __floats2half2_rn(hb.x, hb.y);
    __half2 o1 = __floats2half2_rn(hb.z, hb.w);
    uint2 pk;
    pk.x = *(unsigned int*)&o0;
    pk.y = *(unsigned int*)&o1;
    *(uint2*)&houtH[n * EMB + r4] = pk;
}

// ================= layer 3: pruned fp16 gather (uint2, 8-deep) =================
__global__ __launch_bounds__(256) void k_gg3(const float* __restrict__ hin,
                                             const __half* __restrict__ hinH,
                                             const int* __restrict__ off,
                                             const int* __restrict__ csr,
                                             const int* __restrict__ list,
                                             const int* __restrict__ gcnt,
                                             const float* __restrict__ Wg,
                                             const float* __restrict__ bg,
                                             float* __restrict__ hout) {
    __shared__ float WgL[EMB * EMB];
    __shared__ float aggL[16][EMB + 4];
    int cnt = *gcnt;
    if (blockIdx.x * 16 >= cnt) return;
    int t = threadIdx.x;
    for (int i = t * 4; i < EMB * EMB; i += 256 * 4)
        *(float4*)&WgL[i] = *(const float4*)&Wg[i];
    int g = t >> 4;
    int r4 = (t & 15) * 4;
    int li = blockIdx.x * 16 + g;
    bool act = li < cnt;
    int n = act ? list[li] : 0;
    int s0 = 0, s1 = 0;
    if (act) { s0 = off[n]; s1 = off[n + 1]; }
    float ax = 0.f, ay = 0.f, az = 0.f, aw = 0.f;
    int e = s0;
    for (; e + 8 <= s1; e += 8) {
        int idx[8];
        #pragma unroll
        for (int j = 0; j < 8; ++j) idx[j] = csr[e + j];
        uint2 raw[8];
        #pragma unroll
        for (int j = 0; j < 8; ++j) raw[j] = *(const uint2*)&hinH[idx[j] * EMB + r4];
        #pragma unroll
        for (int j = 0; j < 8; ++j) {
            float2 f0 = __half22float2(*(__half2*)&raw[j].x);
            float2 f1 = __half22float2(*(__half2*)&raw[j].y);
            ax += f0.x; ay += f0.y; az += f1.x; aw += f1.y;
        }
    }
    for (; e < s1; ++e) {
        uint2 raw = *(const uint2*)&hinH[csr[e] * EMB + r4];
        float2 f0 = __half22float2(*(__half2*)&raw.x);
        float2 f1 = __half22float2(*(__half2*)&raw.y);
        ax += f0.x; ay += f0.y; az += f1.x; aw += f1.y;
    }
    aggL[g][r4 + 0] = ax;
    aggL[g][r4 + 1] = ay;
    aggL[g][r4 + 2] = az;
    aggL[g][r4 + 3] = aw;
    __syncthreads();
    float4 acc = *(const float4*)&bg[r4];
    #pragma unroll
    for (int k = 0; k < EMB; ++k) {
        float a = aggL[g][k];
        float4 w = *(const float4*)&WgL[k * EMB + r4];
        acc.x += a * w.x; acc.y += a * w.y; acc.z += a * w.z; acc.w += a * w.w;
    }
    if (act) {
        float4 hb = *(const float4*)&hin[n * EMB + r4];
        hb.x += lrelu(acc.x);
        hb.y += lrelu(acc.y);
        hb.z += lrelu(acc.z);
        hb.w += lrelu(acc.w);
        *(float4*)&hout[n * EMB + r4] = hb;
    }
}

// ================= edge features + MLP.linear (data-parallel) =================
__global__ __launch_bounds__(256) void k_ef(
    const float* __restrict__ h, const int* __restrict__ esrc, const int* __restrict__ edst,
    const int* __restrict__ mask,
    const float* __restrict__ WeS, const float* __restrict__ WeD, const float* __restrict__ be,
    const float* __restrict__ W1, const float* __restrict__ b1,
    const float* __restrict__ W2, const float* __restrict__ b2,
    float* __restrict__ xout)
{
    __shared__ float WeSL[EMB * EMB];
    __shared__ float WeDL[EMB * EMB];
    __shared__ float W1L[EMB * HID];
    __shared__ float hsL[EPB][EMB + 4];
    __shared__ float hdL[EPB][EMB + 4];
    int t = threadIdx.x;
    for (int i = t; i < EMB * EMB / 4; i += 256) {
        ((float4*)WeSL)[i] = ((const float4*)WeS)[i];
        ((float4*)WeDL)[i] = ((const float4*)WeD)[i];
    }
    for (int i = t; i < EMB * HID / 4; i += 256) ((float4*)W1L)[i] = ((const float4*)W1)[i];
    int g = t >> 4, r = t & 15, r4 = r * 4;
    int idx = blockIdx.x * EPB + g;
    int e = mask[idx];
    int s = esrc[e], d = edst[e];
    float4 hs4 = *(const float4*)&h[s * EMB + r4];
    float4 hd4 = *(const float4*)&h[d * EMB + r4];
    *(float4*)&hsL[g][r4] = hs4;
    *(float4*)&hdL[g][r4] = hd4;
    __syncthreads();
    float4 acc = *(const float4*)&be[r4];
    #pragma unroll
    for (int k = 0; k < EMB; ++k) {
        float a = hsL[g][k];
        float c = hdL[g][k];
        float4 w1 = *(const float4*)&WeSL[k * EMB + r4];
        float4 w2 = *(const float4*)&WeDL[k * EMB + r4];
        acc.x += a * w1.x + c * w2.x;
        acc.y += a * w1.y + c * w2.y;
        acc.z += a * w1.z + c * w2.z;
        acc.w += a * w1.w + c * w2.w;
    }
    __syncthreads();
    *(float4*)&hsL[g][r4] = acc;
    __syncthreads();
    float a1 = b1[r], a2 = b1[r + 16];
    #pragma unroll
    for (int k = 0; k < EMB; ++k) {
        float ek = hsL[g][k];
        a1 += ek * W1L[k * HID + r];
        a2 += ek * W1L[k * HID + r + 16];
    }
    float y1 = lrelu(a1), y2 = lrelu(a2);
    float p = y1 * W2[r] + y2 * W2[r + 16];
    p += __shfl_xor(p, 1);
    p += __shfl_xor(p, 2);
    p += __shfl_xor(p, 4);
    p += __shfl_xor(p, 8);
    if (r == 0) xout[idx] = p + b2[0];
}

// ================= decoder =================
__global__ __launch_bounds__(64) void k_dec(const float* __restrict__ xout,
                                            const float* __restrict__ Wd1,
                                            const float* __restrict__ bd1,
                                            const float* __restrict__ Wd2,
                                            const float* __restrict__ bd2,
                                            float* __restrict__ out) {
    int b = blockIdx.x, t = threadIdx.x;
    float z = 0.f;
    if (t < HID) {
        float acc = bd1[t];
        for (int i = 0; i < ES; ++i) acc += xout[b * ES + i] * Wd1[i * HID + t];
        z = lrelu(acc) * Wd2[t];
    }
    z += __shfl_xor(z, 1);
    z += __shfl_xor(z, 2);
    z += __shfl_xor(z, 4);
    z += __shfl_xor(z, 8);
    z += __shfl_xor(z, 16);
    if (t == 0) out[b] = z + bd2[0];
}

extern "C" void kernel_launch(void* const* d_in, const int* in_sizes, int n_in,
                              void* d_out, int out_size, void* d_ws, size_t ws_size,
                              hipStream_t stream) {
    const float* coord = (const float*)d_in[0];
    const int*   esrc  = (const int*)d_in[1];
    const int*   edst  = (const int*)d_in[2];
    const int*   mask  = (const int*)d_in[3];
    const float* Wn    = (const float*)d_in[4];
    const float* bn    = (const float*)d_in[5];
    const float* Wgnn  = (const float*)d_in[6];
    const float* bgnn  = (const float*)d_in[7];
    const float* WeS   = (const float*)d_in[8];
    const float* WeD   = (const float*)d_in[9];
    const float* be    = (const float*)d_in[10];
    const float* W1    = (const float*)d_in[11];
    const float* b1    = (const float*)d_in[12];
    const float* W2    = (const float*)d_in[13];
    const float* b2    = (const float*)d_in[14];
    const float* Wd1   = (const float*)d_in[15];
    const float* bd1   = (const float*)d_in[16];
    const float* Wd2   = (const float*)d_in[17];
    const float* bd2   = (const float*)d_in[18];
    float* out = (float*)d_out;

    char* ws = (char*)d_ws;
    size_t o = 0;
    auto alloc = [&](size_t bytes) {
        void* p = ws + o;
        o = (o + bytes + 255) & ~(size_t)255;
        return p;
    };
    float* hA    = (float*)alloc((size_t)NN * EMB * 4);
    float* hB    = (float*)alloc((size_t)NN * EMB * 4);
    __half* hAh  = (__half*)alloc((size_t)NN * EMB * 2);
    __half* hBh  = (__half*)alloc((size_t)NN * EMB * 2);
    int* off    = (int*)alloc((size_t)(NN + 1) * 4);
    int* csr    = (int*)alloc((size_t)EE * 4);
    int* bp     = (int*)alloc((size_t)EE * 4);
    int* bcnt   = (int*)alloc((size_t)NB * 4);
    int* boff   = (int*)alloc((size_t)(NB + 1) * 4);
    int* bcur   = (int*)alloc((size_t)NB * 4);
    int* perm   = (int*)alloc((size_t)NN * 4);
    int* dcnt   = (int*)alloc((size_t)DBINS * 4);
    int* dcur   = (int*)alloc((size_t)DBINS * 4);
    int* flag   = (int*)alloc((size_t)NN * 4);
    int* list   = (int*)alloc((size_t)NN * 4);
    int* gcnt   = (int*)alloc(256);
    float* xout = (float*)alloc((size_t)BB * ES * 4);
    (void)ws_size; (void)in_sizes; (void)n_in; (void)out_size;

    const float2* coordv = (const float2*)coord;

    // fused scratch zeroing (every launch: harness doesn't re-poison)
    k_zero<<<(NN + 255) / 256, 256, 0, stream>>>(bcnt, dcnt, flag, gcnt);

    // mark masked-edge endpoints (independent of CSR chain)
    k_mark<<<(BB * ES + 255) / 256, 256, 0, stream>>>(mask, esrc, edst, flag);

    // CSR build (+ fused degree histogram)
    k_bhist<<<(EE + 4095) / 4096, 256, 0, stream>>>(edst, bcnt);
    k_bscan<<<1, 512, 0, stream>>>(bcnt, boff, bcur, off);
    k_bin<<<(EE + 2047) / 2048, 256, 0, stream>>>(esrc, edst, bcur, bp);
    k_bcsr<<<NB, 256, 0, stream>>>(boff, bp, off, csr, dcnt);

    // degree-descending permutation (LPT)
    k_dscan<<<1, DBINS, 0, stream>>>(dcnt, dcur);
    k_dperm<<<(NN + 255) / 256, 256, 0, stream>>>(off, dcur, perm);

    // compact needed-node list in perm (degree) order
    k_compact<<<(NN + 255) / 256, 256, 0, stream>>>(perm, flag, list, gcnt);

    // layer 1 (algebraic): h1 fp32 -> hA, fp16 shadow -> hAh
    k_gg0<<<NN / 16, 256, 0, stream>>>(coordv, off, csr, Wn, bn,
                                       Wgnn, bgnn, hA, hAh);

    // layer 2: fp16 gather, fp32 residual; h2 -> hB + hBh
    k_gg<<<NN / 16, 256, 0, stream>>>(hA, hAh, off, csr, perm,
                                      Wgnn + (size_t)1 * EMB * EMB,
                                      bgnn + (size_t)1 * EMB, hB, hBh);

    // layer 3: pruned fp16 gather; h3 rows -> hA
    k_gg3<<<(NN + 15) / 16, 256, 0, stream>>>(hB, hBh, off, csr, list, gcnt,
                                              Wgnn + (size_t)2 * EMB * EMB,
                                              bgnn + (size_t)2 * EMB, hA);

    // masked edgewise features + MLP + decoder
    k_ef<<<BB * ES / EPB, 256, 0, stream>>>(hA, esrc, edst, mask, WeS, WeD, be,
                                            W1, b1, W2, b2, xout);
    k_dec<<<BB, 64, 0, stream>>>(xout, Wd1, bd1, Wd2, bd2, out);
}